// Round 6
// baseline (608.175 us; speedup 1.0000x reference)
//
#include <hip/hip_runtime.h>

#define N_NODES 50000
#define N_EDGES 800000
#define LN_EPS 1e-5f
#define NBLK 196  // ceil(N_NODES/256)

typedef __attribute__((ext_vector_type(8))) short bf16x8;
typedef __attribute__((ext_vector_type(4))) float f32x4;

static __device__ inline unsigned short f2bf(float f) {
  unsigned u = __float_as_uint(f);
  unsigned r = ((u >> 16) & 1) + 0x7fffu;
  return (unsigned short)((u + r) >> 16);
}
static __device__ inline float bf2f(unsigned short u) {
  return __uint_as_float((unsigned)u << 16);
}

// ---- combined edge transforms for all 3 layers: WcT[L][n][k] bf16, bcC[L][n] ----
__global__ void wcomb_kernel(const float* __restrict__ We, const float* __restrict__ be,
                             const float* __restrict__ eW0, const float* __restrict__ eb0,
                             const float* __restrict__ eW1, const float* __restrict__ eb1,
                             const float* __restrict__ eW2, const float* __restrict__ eb2,
                             unsigned short* __restrict__ WcT, float* __restrict__ bcC) {
  int L = blockIdx.x;
  const float* eW = L == 0 ? eW0 : (L == 1 ? eW1 : eW2);
  const float* eb = L == 0 ? eb0 : (L == 1 ? eb1 : eb2);
  int tid = threadIdx.x;
  for (int idx = tid; idx < 64 * 64; idx += 256) {
    int k = idx >> 6, c = idx & 63;
    float s = 0.f;
    for (int j = 0; j < 64; ++j) s = fmaf(We[k * 64 + j], eW[j * 64 + c], s);
    WcT[L * 4096 + c * 64 + k] = f2bf(s);  // transposed: [n][k]
  }
  if (tid < 64) {
    float s = eb[tid];
    for (int j = 0; j < 64; ++j) s = fmaf(be[j], eW[j * 64 + tid], s);
    bcC[L * 64 + tid] = s;
  }
}

// ---- CSC build ----
__global__ void hist_kernel(const int* __restrict__ col, int* __restrict__ deg) {
  int e = blockIdx.x * blockDim.x + threadIdx.x;
  if (e < N_EDGES) atomicAdd(&deg[col[e]], 1);
}

__global__ __launch_bounds__(256) void scan1_kernel(const int* __restrict__ deg,
                                                    int* __restrict__ off, int* __restrict__ bsum) {
  __shared__ int s[256];
  int tid = threadIdx.x, i = blockIdx.x * 256 + tid;
  int v = (i < N_NODES) ? deg[i] : 0;
  s[tid] = v;
  __syncthreads();
  for (int d = 1; d < 256; d <<= 1) {
    int t = (tid >= d) ? s[tid - d] : 0;
    __syncthreads();
    s[tid] += t;
    __syncthreads();
  }
  if (i < N_NODES) off[i] = s[tid] - v;
  if (tid == 255) bsum[blockIdx.x] = s[255];
}

__global__ __launch_bounds__(256) void scan2_kernel(int* __restrict__ bsum) {
  __shared__ int s[256];
  int tid = threadIdx.x;
  int v = (tid < NBLK) ? bsum[tid] : 0;
  s[tid] = v;
  __syncthreads();
  for (int d = 1; d < 256; d <<= 1) {
    int t = (tid >= d) ? s[tid - d] : 0;
    __syncthreads();
    s[tid] += t;
    __syncthreads();
  }
  if (tid < NBLK) bsum[tid] = s[tid] - v;
}

// scan finalize + cursor init + dis = deg^-0.5
__global__ void scan3_kernel(int* __restrict__ off, const int* __restrict__ bsum,
                             int* __restrict__ cursor, const int* __restrict__ deg,
                             float* __restrict__ dis) {
  int i = blockIdx.x * 256 + threadIdx.x;
  if (i < N_NODES) {
    int o = off[i] + bsum[blockIdx.x];
    off[i] = o;
    cursor[i] = o;
    int d = deg[i];
    dis[i] = d > 0 ? rsqrtf((float)d) : 0.f;
  }
}

// fused CSC scatter: position + meta + f32->bf16 attr row permute, single E-pass
__global__ void scatconv_kernel(const int* __restrict__ rowI, const int* __restrict__ colI,
                                const float* __restrict__ dis, int* __restrict__ cursor,
                                const float* __restrict__ attr, int* __restrict__ rowP,
                                float* __restrict__ nrmP, unsigned short* __restrict__ attrP) {
  int e = blockIdx.x * blockDim.x + threadIdx.x;
  if (e >= N_EDGES) return;
  int c = colI[e], r = rowI[e];
  int p = atomicAdd(&cursor[c], 1);
  rowP[p] = r;
  nrmP[p] = dis[r] * dis[c];
  const float* a = attr + (size_t)e * 64;
  unsigned short* o = attrP + (size_t)p * 64;
#pragma unroll
  for (int q = 0; q < 64; q += 4) {
    float4 v = *(const float4*)(a + q);
    ushort4 u = {f2bf(v.x), f2bf(v.y), f2bf(v.z), f2bf(v.w)};
    *(ushort4*)(o + q) = u;
  }
}

// ---- node GEMM K=128 (layer 0), one wave per 64 rows, bf16 out ----
__global__ __launch_bounds__(64) void node_gemm128_kernel(
    const float* __restrict__ X, const float* __restrict__ W, const float* __restrict__ B,
    unsigned short* __restrict__ Y) {
  int row = blockIdx.x * 64 + threadIdx.x;
  int r = row < N_NODES ? row : N_NODES - 1;
  const float* xr = X + (long)r * 128;
  float acc[64];
#pragma unroll
  for (int c = 0; c < 64; ++c) acc[c] = B[c];
#pragma unroll 2
  for (int kb = 0; kb < 128; kb += 8) {
    float4 a0 = *(const float4*)(xr + kb);
    float4 a1 = *(const float4*)(xr + kb + 4);
    float av[8] = {a0.x, a0.y, a0.z, a0.w, a1.x, a1.y, a1.z, a1.w};
#pragma unroll
    for (int kk = 0; kk < 8; ++kk) {
      const float* wr = W + (kb + kk) * 64;
#pragma unroll
      for (int c = 0; c < 64; ++c) acc[c] = fmaf(av[kk], wr[c], acc[c]);
    }
  }
  if (row < N_NODES) {
    unsigned* yo = (unsigned*)(Y + (size_t)row * 64);
#pragma unroll
    for (int c = 0; c < 64; c += 2)
      yo[c >> 1] = (unsigned)f2bf(acc[c]) | ((unsigned)f2bf(acc[c + 1]) << 16);
  }
}

// ---- node GEMM K=64 with fused input ReLU+LayerNorm, bf16 out ----
__global__ __launch_bounds__(64) void node_gemm64_kernel(
    const float* __restrict__ X, const float* __restrict__ W, const float* __restrict__ B,
    const float* __restrict__ G, const float* __restrict__ BT,
    unsigned short* __restrict__ Y) {
  int row = blockIdx.x * 64 + threadIdx.x;
  int r = row < N_NODES ? row : N_NODES - 1;
  const float* xr = X + (long)r * 64;
  float xv[64];
#pragma unroll
  for (int k = 0; k < 64; k += 4) {
    float4 v = *(const float4*)(xr + k);
    xv[k] = v.x; xv[k + 1] = v.y; xv[k + 2] = v.z; xv[k + 3] = v.w;
  }
  float mu = 0.f;
#pragma unroll
  for (int k = 0; k < 64; ++k) { xv[k] = fmaxf(xv[k], 0.f); mu += xv[k]; }
  mu *= (1.f / 64.f);
  float var = 0.f;
#pragma unroll
  for (int k = 0; k < 64; ++k) { float d = xv[k] - mu; var += d * d; }
  float is = rsqrtf(var * (1.f / 64.f) + LN_EPS);
#pragma unroll
  for (int k = 0; k < 64; ++k) xv[k] = (xv[k] - mu) * is * G[k] + BT[k];

  float acc[64];
#pragma unroll
  for (int c = 0; c < 64; ++c) acc[c] = B[c];
#pragma unroll 2
  for (int k = 0; k < 64; ++k) {
    const float* wr = W + k * 64;
#pragma unroll
    for (int c = 0; c < 64; ++c) acc[c] = fmaf(xv[k], wr[c], acc[c]);
  }
  if (row < N_NODES) {
    unsigned* yo = (unsigned*)(Y + (size_t)row * 64);
#pragma unroll
    for (int c = 0; c < 64; c += 2)
      yo[c >> 1] = (unsigned)f2bf(acc[c]) | ((unsigned)f2bf(acc[c + 1]) << 16);
  }
}

// ---- per-destination fused edge GEMM + aggregation: 1 col per wave ----
// MFMA: m = 16 edges, n = 64 channels (4 tiles), k = 64 (2 steps); C-init = bias.
__global__ __launch_bounds__(256, 4) void edge_agg_kernel(
    const unsigned short* __restrict__ attrP, const int* __restrict__ rowP,
    const float* __restrict__ nrmP, const int* __restrict__ offB,
    const int* __restrict__ degI, const unsigned short* __restrict__ WcT,
    const float* __restrict__ bc, const unsigned short* __restrict__ XLb,
    float* __restrict__ OUT) {
  const int lane = threadIdx.x & 63;
  const int lr = lane & 15, lg = lane >> 4;
  const int c = (blockIdx.x * 256 + threadIdx.x) >> 6;  // one col per wave
  if (c >= N_NODES) return;

  // B fragments (WcT[n][k], contiguous in k) + bias
  bf16x8 bfrag[4][2];
  float bias[4];
#pragma unroll
  for (int tn = 0; tn < 4; ++tn) {
    bias[tn] = bc[tn * 16 + lr];
#pragma unroll
    for (int kb = 0; kb < 2; ++kb)
      bfrag[tn][kb] = *(const bf16x8*)(WcT + (tn * 16 + lr) * 64 + kb * 32 + lg * 8);
  }

  const int off = offB[c], deg = degI[c];
  const int last = off + (deg > 0 ? deg - 1 : 0);
  float fsum[4] = {0.f, 0.f, 0.f, 0.f};
#pragma unroll 1
  for (int b = 0; b < deg; b += 16) {
    // A fragment: row = edge (lr), k-chunk = lg*8
    int ea = min(off + b + lr, last);
    const unsigned short* ap = attrP + (size_t)ea * 64 + lg * 8;
    bf16x8 a0 = *(const bf16x8*)(ap);
    bf16x8 a1 = *(const bf16x8*)(ap + 32);
    // per-edge meta for this lane's 4 output rows (edges b+lg*4+j)
    float nm[4]; int rj[4];
#pragma unroll
    for (int j = 0; j < 4; ++j) {
      int idx = b + lg * 4 + j;
      int e = min(off + idx, last);
      nm[j] = (idx < deg) ? nrmP[e] : 0.f;
      rj[j] = rowP[e];
    }
    // x gathers: 16 independent 2B loads, issued up front
    unsigned short xg[4][4];
#pragma unroll
    for (int j = 0; j < 4; ++j)
#pragma unroll
      for (int tn = 0; tn < 4; ++tn)
        xg[j][tn] = XLb[(size_t)rj[j] * 64 + tn * 16 + lr];
    // 8 MFMA, C initialized with per-channel bias
    f32x4 acc[4];
#pragma unroll
    for (int tn = 0; tn < 4; ++tn) {
      f32x4 z = {bias[tn], bias[tn], bias[tn], bias[tn]};
      z = __builtin_amdgcn_mfma_f32_16x16x32_bf16(a0, bfrag[tn][0], z, 0, 0, 0);
      z = __builtin_amdgcn_mfma_f32_16x16x32_bf16(a1, bfrag[tn][1], z, 0, 0, 0);
      acc[tn] = z;
    }
    // epilogue: msg = ef * nrm * x[row], accumulate
#pragma unroll
    for (int tn = 0; tn < 4; ++tn)
#pragma unroll
      for (int j = 0; j < 4; ++j)
        fsum[tn] = fmaf(acc[tn][j] * nm[j], bf2f(xg[j][tn]), fsum[tn]);
  }
  // reduce over the 4 lane-groups (edge sub-batches)
#pragma unroll
  for (int tn = 0; tn < 4; ++tn) {
    fsum[tn] += __shfl_xor(fsum[tn], 16);
    fsum[tn] += __shfl_xor(fsum[tn], 32);
  }
  if (lg == 0) {
#pragma unroll
    for (int tn = 0; tn < 4; ++tn)
      OUT[(size_t)c * 64 + tn * 16 + lr] = fsum[tn];
  }
}

extern "C" void kernel_launch(void* const* d_in, const int* in_sizes, int n_in,
                              void* d_out, int out_size, void* d_ws, size_t ws_size,
                              hipStream_t stream) {
  const float* x    = (const float*)d_in[0];
  const int* eidx   = (const int*)d_in[1];
  const float* attr = (const float*)d_in[2];
  const float* We  = (const float*)d_in[3];
  const float* be  = (const float*)d_in[4];
  const float* W0  = (const float*)d_in[5];  const float* b0  = (const float*)d_in[6];
  const float* eW0 = (const float*)d_in[7];  const float* eb0 = (const float*)d_in[8];
  const float* W1  = (const float*)d_in[9];  const float* b1  = (const float*)d_in[10];
  const float* eW1 = (const float*)d_in[11]; const float* eb1 = (const float*)d_in[12];
  const float* W2  = (const float*)d_in[13]; const float* b2  = (const float*)d_in[14];
  const float* eW2 = (const float*)d_in[15]; const float* eb2 = (const float*)d_in[16];
  const float* g0  = (const float*)d_in[17]; const float* bt0 = (const float*)d_in[18];
  const float* g1  = (const float*)d_in[19]; const float* bt1 = (const float*)d_in[20];
  const int* rowI = eidx;
  const int* colI = eidx + N_EDGES;

  char* base = (char*)d_ws;
  size_t pos = 0;
  auto alloc = [&](size_t b) -> char* {
    char* p = base + pos;
    pos += (b + 255) & ~(size_t)255;
    return p;
  };
  unsigned short* XLb = (unsigned short*)alloc((size_t)N_NODES * 64 * 2);
  float* hB   = (float*)alloc((size_t)N_NODES * 64 * 4);
  float* nrmP = (float*)alloc((size_t)N_EDGES * 4);
  int* rowP   = (int*)alloc((size_t)N_EDGES * 4);
  int* degI   = (int*)alloc((size_t)N_NODES * 4);
  float* disF = (float*)alloc((size_t)N_NODES * 4);
  int* offB   = (int*)alloc((size_t)N_NODES * 4);
  int* curB   = (int*)alloc((size_t)N_NODES * 4);
  int* bsum   = (int*)alloc(256 * 4);
  unsigned short* WcT = (unsigned short*)alloc(3 * 4096 * 2);
  float* bcC  = (float*)alloc(3 * 64 * 4);
  unsigned short* attrP = (unsigned short*)alloc((size_t)N_EDGES * 64 * 2);
  (void)ws_size;
  float* out = (float*)d_out;

  // CSC build (sorted by destination col) + fused meta + attr bf16 permute
  hipMemsetAsync(degI, 0, (size_t)N_NODES * 4, stream);
  hist_kernel<<<N_EDGES / 256, 256, 0, stream>>>(colI, degI);
  scan1_kernel<<<NBLK, 256, 0, stream>>>(degI, offB, bsum);
  scan2_kernel<<<1, 256, 0, stream>>>(bsum);
  scan3_kernel<<<NBLK, 256, 0, stream>>>(offB, bsum, curB, degI, disF);
  scatconv_kernel<<<N_EDGES / 256, 256, 0, stream>>>(rowI, colI, disF, curB, attr, rowP, nrmP, attrP);
  wcomb_kernel<<<3, 256, 0, stream>>>(We, be, eW0, eb0, eW1, eb1, eW2, eb2, WcT, bcC);

  const int gemm_grid = (N_NODES + 63) / 64;
  const int agg_grid = (N_NODES + 3) / 4;  // 1 col/wave, 4 waves/block
  // layer 0
  node_gemm128_kernel<<<gemm_grid, 64, 0, stream>>>(x, W0, b0, XLb);
  edge_agg_kernel<<<agg_grid, 256, 0, stream>>>(attrP, rowP, nrmP, offB, degI, WcT, bcC, XLb, hB);
  // layer 1 (input ReLU+LN fused into node GEMM)
  node_gemm64_kernel<<<gemm_grid, 64, 0, stream>>>(hB, W1, b1, g0, bt0, XLb);
  edge_agg_kernel<<<agg_grid, 256, 0, stream>>>(attrP, rowP, nrmP, offB, degI, WcT + 4096, bcC + 64, XLb, hB);
  // layer 2
  node_gemm64_kernel<<<gemm_grid, 64, 0, stream>>>(hB, W2, b2, g1, bt1, XLb);
  edge_agg_kernel<<<agg_grid, 256, 0, stream>>>(attrP, rowP, nrmP, offB, degI, WcT + 8192, bcC + 128, XLb, out);
}